// Round 1
// baseline (188.474 us; speedup 1.0000x reference)
//
#include <hip/hip_runtime.h>

#define B_ 2
#define L_ 2048
#define H_ 8
#define D_ 64
#define W_ 16        // LOCAL_WINDOW/2
#define SP_ 65       // STRIDE+1
#define NC_ 16
#define CHUNK_ 128   // L_/NC_

// ---------------- Kernel 1: per-(b,h) chunk sums of values ----------------
// grid = B*H*NC blocks, 64 threads (one per dim d)
__global__ void chunk_sums_k(const float* __restrict__ v, float* __restrict__ csum) {
    int blk = blockIdx.x;
    int c = blk % NC_;
    int h = (blk / NC_) % H_;
    int b = blk / (NC_ * H_);
    int d = threadIdx.x;
    float s = 0.f;
    int l0 = c * CHUNK_;
    for (int l = l0; l < l0 + CHUNK_; ++l)
        s += v[((b * L_ + l) * H_ + h) * D_ + d];
    csum[((b * H_ + h) * NC_ + c) * D_ + d] = s;
}

// ---------------- Kernel 2: inclusive prefix of values into P (bhld) ------
// grid = B*H*NC blocks, 64 threads
__global__ void prefix_k(const float* __restrict__ v, const float* __restrict__ csum,
                         float* __restrict__ P) {
    int blk = blockIdx.x;
    int c = blk % NC_;
    int h = (blk / NC_) % H_;
    int b = blk / (NC_ * H_);
    int d = threadIdx.x;
    float run = 0.f;
    for (int cc = 0; cc < c; ++cc)
        run += csum[((b * H_ + h) * NC_ + cc) * D_ + d];
    int l0 = c * CHUNK_;
    for (int l = l0; l < l0 + CHUNK_; ++l) {
        run += v[((b * L_ + l) * H_ + h) * D_ + d];
        P[((b * H_ + h) * L_ + l) * D_ + d] = run;
    }
}

// ---------------- Kernel 3: sparse attention, one wave per query row ------
// out[b,i,h,d] = (sum_{j in S} (e^{0.125 q·k_j} - 1) v_j[d] + P_i[d]) / (z + i+1)
__global__ __launch_bounds__(256) void dozer_k(const float* __restrict__ q,
                                               const float* __restrict__ k,
                                               const float* __restrict__ v,
                                               const float* __restrict__ P,
                                               float* __restrict__ out) {
    int gtid = blockIdx.x * blockDim.x + threadIdx.x;
    int wave = gtid >> 6;           // one wave per (b,h,i) row; consecutive waves -> consecutive i
    int lane = threadIdx.x & 63;
    int i = wave % L_;
    int h = (wave / L_) % H_;
    int b = wave / (L_ * H_);

    const float qv = q[((b * L_ + i) * H_ + h) * D_ + lane];
    float acc = 0.f;
    float z   = 0.f;

    // local window: j in [max(0, i-16), i]
    int jmin = (i > W_) ? (i - W_) : 0;
    for (int j = jmin; j <= i; ++j) {
        int base = ((b * L_ + j) * H_ + h) * D_;
        float part = qv * k[base + lane];
        #pragma unroll
        for (int m = 32; m; m >>= 1) part += __shfl_xor(part, m, 64);
        float w = __expf(0.125f * part) - 1.f;
        acc += w * v[base + lane];
        z   += w;
    }
    // strided: j = i - 65*t, t >= 1 (t=0 already covered by local, 65 > 16 so no overlap)
    for (int off = SP_; off <= i; off += SP_) {
        int j = i - off;
        int base = ((b * L_ + j) * H_ + h) * D_;
        float part = qv * k[base + lane];
        #pragma unroll
        for (int m = 32; m; m >>= 1) part += __shfl_xor(part, m, 64);
        float w = __expf(0.125f * part) - 1.f;
        acc += w * v[base + lane];
        z   += w;
    }

    float p = P[((b * H_ + h) * L_ + i) * D_ + lane];
    out[((b * L_ + i) * H_ + h) * D_ + lane] = (acc + p) / (z + (float)(i + 1));
}

extern "C" void kernel_launch(void* const* d_in, const int* in_sizes, int n_in,
                              void* d_out, int out_size, void* d_ws, size_t ws_size,
                              hipStream_t stream) {
    const float* q = (const float*)d_in[0];
    const float* k = (const float*)d_in[1];
    const float* v = (const float*)d_in[2];
    // d_in[3] = attn_mask: deterministic causal — not read.
    float* out = (float*)d_out;

    float* csum = (float*)d_ws;                       // B*H*NC*D  = 16384 floats
    float* P    = csum + (size_t)B_ * H_ * NC_ * D_;  // B*H*L*D   = 2097152 floats

    chunk_sums_k<<<B_ * H_ * NC_, 64, 0, stream>>>(v, csum);
    prefix_k   <<<B_ * H_ * NC_, 64, 0, stream>>>(v, csum, P);

    int rows = B_ * H_ * L_;                          // 32768 waves
    dozer_k<<<rows / 4, 256, 0, stream>>>(q, k, v, P, out);
}

// Round 2
// 137.363 us; speedup vs baseline: 1.3721x; 1.3721x over previous
//
#include <hip/hip_runtime.h>

#define B_ 2
#define L_ 2048
#define H_ 8
#define D_ 64
#define W_ 16        // LOCAL_WINDOW/2
#define SP_ 65       // STRIDE+1
#define NC_ 128
#define CHUNK_ 16    // L_/NC_

// ---------------- Kernel 1: per-(b,h) chunk sums of values ----------------
// grid = B*H*NC blocks, 64 threads (one per dim d)
__global__ void chunk_sums_k(const float* __restrict__ v, float* __restrict__ csum) {
    int blk = blockIdx.x;
    int c  = blk % NC_;
    int bh = blk / NC_;          // b*H + h
    int h = bh % H_;
    int b = bh / H_;
    int d = threadIdx.x;
    float s = 0.f;
    int l0 = c * CHUNK_;
    for (int l = l0; l < l0 + CHUNK_; ++l)
        s += v[((b * L_ + l) * H_ + h) * D_ + d];
    csum[(bh * NC_ + c) * D_ + d] = s;
}

// ---------------- Kernel 2: sparse attention, one wave per query row ------
// Wave layout: 4 groups x 16 lanes; lane owns dims [4s,4s+4) as float4;
// group g handles every 4th selected column -> 4 columns per wave instruction,
// butterfly reduce is 4 steps within the 16-lane group.
// out[b,i,h,:] = (sum_{j in S} (e^{s_ij}-1) v_j + prefix_i) / (z + i + 1)
// prefix_i folded as: full chunks from csum + partial-chunk rows via +1 weight
// inside the local-window loop (partial rows are always a subset of the window).
__global__ __launch_bounds__(256) void dozer_k(const float* __restrict__ q,
                                               const float* __restrict__ k,
                                               const float* __restrict__ v,
                                               const float* __restrict__ csum,
                                               float* __restrict__ out) {
    int gtid = blockIdx.x * blockDim.x + threadIdx.x;
    int wave = gtid >> 6;
    int lane = threadIdx.x & 63;
    int grp  = lane >> 4;        // 0..3
    int sub  = lane & 15;        // owns dims 4*sub .. 4*sub+3
    int i  = wave % L_;
    int hh = (wave / L_) % H_;
    int b  = wave / (L_ * H_);
    int bh = b * H_ + hh;

    const int rowstride = H_ * D_;   // 512 floats between consecutive seq rows
    const float* qp = q + ((size_t)(b * L_ + i) * H_ + hh) * D_ + 4 * sub;
    float4 q4 = *(const float4*)qp;

    const float* kbase = k + ((size_t)b * L_ * H_ + hh) * D_ + 4 * sub;
    const float* vbase = v + ((size_t)b * L_ * H_ + hh) * D_ + 4 * sub;

    float4 numer = make_float4(0.f, 0.f, 0.f, 0.f);
    float z = 0.f;

    int c      = i >> 4;         // chunk index of row i (CHUNK_=16)
    int pstart = c << 4;         // first row of the partial chunk

    // ---- local window: offsets o = 0..min(i,16); group g takes o = g, g+4, ...
    int omax = (i < W_) ? i : W_;
    for (int o = grp; o <= omax; o += 4) {
        int j = i - o;
        float4 k4 = *(const float4*)(kbase + (size_t)j * rowstride);
        float4 v4 = *(const float4*)(vbase + (size_t)j * rowstride);
        float part = q4.x * k4.x + q4.y * k4.y + q4.z * k4.z + q4.w * k4.w;
        part += __shfl_xor(part, 1, 64);
        part += __shfl_xor(part, 2, 64);
        part += __shfl_xor(part, 4, 64);
        part += __shfl_xor(part, 8, 64);
        float we = __expf(0.125f * part) - 1.f;
        z += we;
        float wv = we + ((j >= pstart) ? 1.f : 0.f);  // fold partial-prefix row
        numer.x += wv * v4.x; numer.y += wv * v4.y;
        numer.z += wv * v4.z; numer.w += wv * v4.w;
    }

    // ---- strided: j = i - 65*t, t = 1..i/65; group g takes t = 1+g, 5+g, ...
    int tmax = i / SP_;
    for (int t = 1 + grp; t <= tmax; t += 4) {
        int j = i - SP_ * t;
        float4 k4 = *(const float4*)(kbase + (size_t)j * rowstride);
        float4 v4 = *(const float4*)(vbase + (size_t)j * rowstride);
        float part = q4.x * k4.x + q4.y * k4.y + q4.z * k4.z + q4.w * k4.w;
        part += __shfl_xor(part, 1, 64);
        part += __shfl_xor(part, 2, 64);
        part += __shfl_xor(part, 4, 64);
        part += __shfl_xor(part, 8, 64);
        float we = __expf(0.125f * part) - 1.f;
        z += we;
        numer.x += we * v4.x; numer.y += we * v4.y;
        numer.z += we * v4.z; numer.w += we * v4.w;
    }

    // ---- full-chunk prefix sums: group g takes cc = g, g+4, ... < c
    const float* cs = csum + (size_t)bh * NC_ * D_ + 4 * sub;
    for (int cc = grp; cc < c; cc += 4) {
        float4 c4 = *(const float4*)(cs + (size_t)cc * D_);
        numer.x += c4.x; numer.y += c4.y; numer.z += c4.z; numer.w += c4.w;
    }

    // ---- cross-group reduction (lanes xor 16, 32)
    #pragma unroll
    for (int m = 16; m <= 32; m <<= 1) {
        numer.x += __shfl_xor(numer.x, m, 64);
        numer.y += __shfl_xor(numer.y, m, 64);
        numer.z += __shfl_xor(numer.z, m, 64);
        numer.w += __shfl_xor(numer.w, m, 64);
        z       += __shfl_xor(z, m, 64);
    }

    if (lane < 16) {
        float inv = 1.f / (z + (float)(i + 1));
        float4 o4 = make_float4(numer.x * inv, numer.y * inv,
                                numer.z * inv, numer.w * inv);
        *(float4*)(out + ((size_t)(b * L_ + i) * H_ + hh) * D_ + 4 * sub) = o4;
    }
}

extern "C" void kernel_launch(void* const* d_in, const int* in_sizes, int n_in,
                              void* d_out, int out_size, void* d_ws, size_t ws_size,
                              hipStream_t stream) {
    const float* q = (const float*)d_in[0];
    const float* k = (const float*)d_in[1];
    const float* v = (const float*)d_in[2];
    // d_in[3] = attn_mask: deterministic causal — not read.
    float* out = (float*)d_out;

    float* csum = (float*)d_ws;  // B*H*NC*D = 131072 floats (512 KB)

    chunk_sums_k<<<B_ * H_ * NC_, 64, 0, stream>>>(v, csum);

    int rows = B_ * H_ * L_;     // 32768 waves, 4 per 256-thread block
    dozer_k<<<rows / 4, 256, 0, stream>>>(q, k, v, csum, out);
}

// Round 3
// 124.466 us; speedup vs baseline: 1.5143x; 1.1036x over previous
//
#include <hip/hip_runtime.h>

#define B_ 2
#define L_ 2048
#define H_ 8
#define D_ 64
#define W_ 16        // LOCAL_WINDOW/2
#define SP_ 65       // STRIDE+1
#define NC_ 128      // level-1 chunks per (b,h), chunk = 16 rows
#define NL2_ 8       // level-2 chunks per (b,h), chunk = 256 rows

// ---------------- Kernel 1: level-1 chunk sums of values (chunk = 16 rows) --
// grid = B*H*NC blocks, 64 threads (one per dim d)
__global__ void chunk_sums_k(const float* __restrict__ v, float* __restrict__ csum1) {
    int blk = blockIdx.x;
    int c  = blk % NC_;
    int bh = blk / NC_;          // b*H + h
    int h = bh % H_;
    int b = bh / H_;
    int d = threadIdx.x;
    float s = 0.f;
    int l0 = c * 16;
    #pragma unroll
    for (int l = 0; l < 16; ++l)
        s += v[((b * L_ + l0 + l) * H_ + h) * D_ + d];
    csum1[(bh * NC_ + c) * D_ + d] = s;
}

// ---------------- Kernel 2: level-2 sums (chunk = 256 rows = 16 level-1) ----
// grid = B*H*NL2 blocks, 64 threads
__global__ void l2_sums_k(const float* __restrict__ csum1, float* __restrict__ csum2) {
    int blk = blockIdx.x;
    int c2 = blk % NL2_;
    int bh = blk / NL2_;
    int d  = threadIdx.x;
    float s = 0.f;
    #pragma unroll
    for (int cc = 0; cc < 16; ++cc)
        s += csum1[(bh * NC_ + c2 * 16 + cc) * D_ + d];
    csum2[(bh * NL2_ + c2) * D_ + d] = s;
}

// ---------------- Kernel 3: sparse attention, one wave per query row --------
// Wave = 8 groups x 8 lanes; lane owns dims [8*sub, 8*sub+8) as 2x float4.
// Group g takes every 8th selected column -> 8 columns per wave-iteration,
// dot-reduce = 3 shuffle steps within the 8-lane group.
// out = (sum_{j in S} (e^{s_ij}-1) v_j + prefix_i) / (z + i + 1), where
// prefix_i = level-2 chunks + level-1 chunks + partial rows folded (+1 weight)
// into the local-window loop (partial level-1 rows are a subset of the window).
__global__ __launch_bounds__(256) void dozer_k(const float* __restrict__ q,
                                               const float* __restrict__ k,
                                               const float* __restrict__ v,
                                               const float* __restrict__ csum1,
                                               const float* __restrict__ csum2,
                                               float* __restrict__ out) {
    int gtid = blockIdx.x * blockDim.x + threadIdx.x;
    int wave = gtid >> 6;
    int lane = threadIdx.x & 63;
    int grp  = lane >> 3;        // 0..7
    int sub  = lane & 7;         // owns dims 8*sub..8*sub+7
    int i  = wave % L_;
    int hh = (wave / L_) % H_;
    int b  = wave / (L_ * H_);
    int bh = b * H_ + hh;

    const int rowstride = H_ * D_;   // 512 floats between consecutive seq rows
    const float* qp = q + ((size_t)(b * L_ + i) * H_ + hh) * D_ + 8 * sub;
    float4 qa = *(const float4*)qp;
    float4 qb = *(const float4*)(qp + 4);

    const float* kbase = k + ((size_t)b * L_ * H_ + hh) * D_ + 8 * sub;
    const float* vbase = v + ((size_t)b * L_ * H_ + hh) * D_ + 8 * sub;

    float4 na = make_float4(0.f, 0.f, 0.f, 0.f);
    float4 nb = make_float4(0.f, 0.f, 0.f, 0.f);
    float z = 0.f;

    int c1 = i >> 4;             // level-1 chunk of row i
    int c2 = i >> 8;             // level-2 chunk of row i
    int pstart = c1 << 4;        // first row of partial level-1 chunk

    // ---- local window: o = 0..min(i,16); group g takes o = g, g+8, (g+16)
    int omax = (i < W_) ? i : W_;
    for (int o = grp; o <= omax; o += 8) {
        int j = i - o;
        const float* kr = kbase + (size_t)j * rowstride;
        const float* vr = vbase + (size_t)j * rowstride;
        float4 ka = *(const float4*)kr;
        float4 kb = *(const float4*)(kr + 4);
        float4 va = *(const float4*)vr;
        float4 vb = *(const float4*)(vr + 4);
        float part = qa.x * ka.x + qa.y * ka.y + qa.z * ka.z + qa.w * ka.w
                   + qb.x * kb.x + qb.y * kb.y + qb.z * kb.z + qb.w * kb.w;
        part += __shfl_xor(part, 1, 64);
        part += __shfl_xor(part, 2, 64);
        part += __shfl_xor(part, 4, 64);
        float we = __expf(0.125f * part) - 1.f;
        z += we;
        float wv = we + ((j >= pstart) ? 1.f : 0.f);  // fold partial prefix row
        na.x += wv * va.x; na.y += wv * va.y; na.z += wv * va.z; na.w += wv * va.w;
        nb.x += wv * vb.x; nb.y += wv * vb.y; nb.z += wv * vb.z; nb.w += wv * vb.w;
    }

    // ---- strided: j = i - 65*t, t = 1..i/65; group g takes t = 1+g, 9+g, ...
    int tmax = i / SP_;
    for (int t = 1 + grp; t <= tmax; t += 8) {
        int j = i - SP_ * t;
        const float* kr = kbase + (size_t)j * rowstride;
        const float* vr = vbase + (size_t)j * rowstride;
        float4 ka = *(const float4*)kr;
        float4 kb = *(const float4*)(kr + 4);
        float4 va = *(const float4*)vr;
        float4 vb = *(const float4*)(vr + 4);
        float part = qa.x * ka.x + qa.y * ka.y + qa.z * ka.z + qa.w * ka.w
                   + qb.x * kb.x + qb.y * kb.y + qb.z * kb.z + qb.w * kb.w;
        part += __shfl_xor(part, 1, 64);
        part += __shfl_xor(part, 2, 64);
        part += __shfl_xor(part, 4, 64);
        float we = __expf(0.125f * part) - 1.f;
        z += we;
        na.x += we * va.x; na.y += we * va.y; na.z += we * va.z; na.w += we * va.w;
        nb.x += we * vb.x; nb.y += we * vb.y; nb.z += we * vb.z; nb.w += we * vb.w;
    }

    // ---- level-2 prefix chunks: cc2 < c2 (c2 <= 7 -> at most 1 per group)
    const float* cs2 = csum2 + ((size_t)bh * NL2_) * D_ + 8 * sub;
    for (int cc = grp; cc < c2; cc += 8) {
        float4 a = *(const float4*)(cs2 + (size_t)cc * D_);
        float4 bb = *(const float4*)(cs2 + (size_t)cc * D_ + 4);
        na.x += a.x; na.y += a.y; na.z += a.z; na.w += a.w;
        nb.x += bb.x; nb.y += bb.y; nb.z += bb.z; nb.w += bb.w;
    }
    // ---- level-1 chunks inside the current level-2 (0..15 of them)
    const float* cs1 = csum1 + ((size_t)bh * NC_) * D_ + 8 * sub;
    for (int cc = (c2 << 4) + grp; cc < c1; cc += 8) {
        float4 a = *(const float4*)(cs1 + (size_t)cc * D_);
        float4 bb = *(const float4*)(cs1 + (size_t)cc * D_ + 4);
        na.x += a.x; na.y += a.y; na.z += a.z; na.w += a.w;
        nb.x += bb.x; nb.y += bb.y; nb.z += bb.z; nb.w += bb.w;
    }

    // ---- cross-group reduction (xor 8, 16, 32)
    #pragma unroll
    for (int m = 8; m <= 32; m <<= 1) {
        na.x += __shfl_xor(na.x, m, 64); na.y += __shfl_xor(na.y, m, 64);
        na.z += __shfl_xor(na.z, m, 64); na.w += __shfl_xor(na.w, m, 64);
        nb.x += __shfl_xor(nb.x, m, 64); nb.y += __shfl_xor(nb.y, m, 64);
        nb.z += __shfl_xor(nb.z, m, 64); nb.w += __shfl_xor(nb.w, m, 64);
        z    += __shfl_xor(z, m, 64);
    }

    if (lane < 8) {
        float inv = 1.f / (z + (float)(i + 1));
        float* op = out + ((size_t)(b * L_ + i) * H_ + hh) * D_ + 8 * sub;
        float4 oa = make_float4(na.x * inv, na.y * inv, na.z * inv, na.w * inv);
        float4 ob = make_float4(nb.x * inv, nb.y * inv, nb.z * inv, nb.w * inv);
        *(float4*)op = oa;
        *(float4*)(op + 4) = ob;
    }
}

extern "C" void kernel_launch(void* const* d_in, const int* in_sizes, int n_in,
                              void* d_out, int out_size, void* d_ws, size_t ws_size,
                              hipStream_t stream) {
    const float* q = (const float*)d_in[0];
    const float* k = (const float*)d_in[1];
    const float* v = (const float*)d_in[2];
    // d_in[3] = attn_mask: deterministic causal — not read.
    float* out = (float*)d_out;

    float* csum1 = (float*)d_ws;                         // B*H*NC*D  = 131072 floats
    float* csum2 = csum1 + (size_t)B_ * H_ * NC_ * D_;   // B*H*NL2*D = 8192 floats

    chunk_sums_k<<<B_ * H_ * NC_, 64, 0, stream>>>(v, csum1);
    l2_sums_k   <<<B_ * H_ * NL2_, 64, 0, stream>>>(csum1, csum2);

    int rows = B_ * H_ * L_;     // 32768 waves, 4 per 256-thread block
    dozer_k<<<rows / 4, 256, 0, stream>>>(q, k, v, csum1, csum2, out);
}

// Round 4
// 123.090 us; speedup vs baseline: 1.5312x; 1.0112x over previous
//
#include <hip/hip_runtime.h>

#define B_ 2
#define L_ 2048
#define H_ 8
#define D_ 64
#define W_ 16        // LOCAL_WINDOW/2
#define SP_ 65       // STRIDE+1
#define NC_ 128      // level-1 chunks per (b,h), chunk = 16 rows
#define NL2_ 8       // level-2 chunks per (b,h), chunk = 256 rows

// ---------------- Kernel 1: level-1 chunk sums of values (chunk = 16 rows) --
__global__ void chunk_sums_k(const float* __restrict__ v, float* __restrict__ csum1) {
    int blk = blockIdx.x;
    int c  = blk % NC_;
    int bh = blk / NC_;
    int h = bh % H_;
    int b = bh / H_;
    int d = threadIdx.x;
    float s = 0.f;
    int l0 = c * 16;
    #pragma unroll
    for (int l = 0; l < 16; ++l)
        s += v[((b * L_ + l0 + l) * H_ + h) * D_ + d];
    csum1[(bh * NC_ + c) * D_ + d] = s;
}

// ---------------- Kernel 2: level-2 sums (chunk = 256 rows = 16 level-1) ----
__global__ void l2_sums_k(const float* __restrict__ csum1, float* __restrict__ csum2) {
    int blk = blockIdx.x;
    int c2 = blk % NL2_;
    int bh = blk / NL2_;
    int d  = threadIdx.x;
    float s = 0.f;
    #pragma unroll
    for (int cc = 0; cc < 16; ++cc)
        s += csum1[(bh * NC_ + c2 * 16 + cc) * D_ + d];
    csum2[(bh * NL2_ + c2) * D_ + d] = s;
}

// ---------------- Kernel 3: one wave per ROW PAIR (2r, 2r+1) ----------------
// Wave = 8 groups x 8 lanes; lane owns dims [8*sub, 8*sub+8).
// Local union window (18 offsets) shares one K/V load between both rows' dot
// chains; strided sets are disjoint (2 loads, 2 chains). Prefix chunks are
// identical for the pair (chunk boundaries even) -> computed once.
__global__ __launch_bounds__(256) void dozer_k(const float* __restrict__ q,
                                               const float* __restrict__ k,
                                               const float* __restrict__ v,
                                               const float* __restrict__ csum1,
                                               const float* __restrict__ csum2,
                                               float* __restrict__ out) {
    int gtid = blockIdx.x * blockDim.x + threadIdx.x;
    int wave = gtid >> 6;
    int lane = threadIdx.x & 63;
    int grp  = lane >> 3;        // 0..7
    int sub  = lane & 7;         // owns dims 8*sub..8*sub+7
    int pr = wave % (L_ / 2);
    int hh = (wave / (L_ / 2)) % H_;
    int b  = wave / ((L_ / 2) * H_);
    int bh = b * H_ + hh;
    int ia = 2 * pr;
    int ib = ia + 1;

    const int rs = H_ * D_;      // 512 floats between consecutive seq rows
    const float* qpa = q + ((size_t)(b * L_ + ia) * H_ + hh) * D_ + 8 * sub;
    float4 qa0 = *(const float4*)qpa;
    float4 qa1 = *(const float4*)(qpa + 4);
    float4 qb0 = *(const float4*)(qpa + rs);
    float4 qb1 = *(const float4*)(qpa + rs + 4);

    const float* kbase = k + ((size_t)b * L_ * H_ + hh) * D_ + 8 * sub;
    const float* vbase = v + ((size_t)b * L_ * H_ + hh) * D_ + 8 * sub;

    float4 na0 = make_float4(0.f,0.f,0.f,0.f), na1 = na0;
    float4 nb0 = na0, nb1 = na0;
    float za = 0.f, zb = 0.f;

    int c1 = ia >> 4;            // level-1 chunk (same for ia, ib)
    int c2 = ia >> 8;            // level-2 chunk (same for ia, ib)
    int pstart = c1 << 4;

    // ---- local union window: o = 0..17, j = ib - o; group g takes o=g,g+8,g+16
    #pragma unroll
    for (int it = 0; it < 3; ++it) {
        int o = grp + 8 * it;
        int j = ib - o;
        bool jok = (o <= 17) && (j >= 0);
        int jc = jok ? j : 0;
        const float* kr = kbase + (size_t)jc * rs;
        const float* vr = vbase + (size_t)jc * rs;
        float4 k0 = *(const float4*)kr;
        float4 k1 = *(const float4*)(kr + 4);
        float4 v0 = *(const float4*)vr;
        float4 v1 = *(const float4*)(vr + 4);
        float pa = qa0.x*k0.x + qa0.y*k0.y + qa0.z*k0.z + qa0.w*k0.w
                 + qa1.x*k1.x + qa1.y*k1.y + qa1.z*k1.z + qa1.w*k1.w;
        float pb = qb0.x*k0.x + qb0.y*k0.y + qb0.z*k0.z + qb0.w*k0.w
                 + qb1.x*k1.x + qb1.y*k1.y + qb1.z*k1.z + qb1.w*k1.w;
        pa += __shfl_xor(pa, 1, 64); pb += __shfl_xor(pb, 1, 64);
        pa += __shfl_xor(pa, 2, 64); pb += __shfl_xor(pb, 2, 64);
        pa += __shfl_xor(pa, 4, 64); pb += __shfl_xor(pb, 4, 64);
        bool act_a = jok && (o >= 1);   // a-window: j in [ia-16, ia]
        bool act_b = jok && (o <= 16);  // b-window: j in [ib-16, ib]
        float wa = act_a ? (__expf(0.125f * pa) - 1.f) : 0.f;
        float wb = act_b ? (__expf(0.125f * pb) - 1.f) : 0.f;
        za += wa; zb += wb;
        float fa = wa + ((jok && o >= 1 && j >= pstart) ? 1.f : 0.f);
        float fb = wb + ((jok && j >= pstart) ? 1.f : 0.f);
        na0.x += fa*v0.x; na0.y += fa*v0.y; na0.z += fa*v0.z; na0.w += fa*v0.w;
        na1.x += fa*v1.x; na1.y += fa*v1.y; na1.z += fa*v1.z; na1.w += fa*v1.w;
        nb0.x += fb*v0.x; nb0.y += fb*v0.y; nb0.z += fb*v0.z; nb0.w += fb*v0.w;
        nb1.x += fb*v1.x; nb1.y += fb*v1.y; nb1.z += fb*v1.z; nb1.w += fb*v1.w;
    }

    // ---- strided: t = 1..ib/65; j_b = ib-65t, j_a = j_b-1 (disjoint sets)
    int tmax = ib / SP_;
    for (int t = 1 + grp; t <= tmax; t += 8) {
        int jb = ib - SP_ * t;
        int ja = jb - 1;
        bool aok = (ja >= 0);
        int jac = aok ? ja : 0;
        const float* kra = kbase + (size_t)jac * rs;
        const float* vra = vbase + (size_t)jac * rs;
        const float* krb = kbase + (size_t)jb * rs;
        const float* vrb = vbase + (size_t)jb * rs;
        float4 ka0 = *(const float4*)kra;
        float4 ka1 = *(const float4*)(kra + 4);
        float4 kb0 = *(const float4*)krb;
        float4 kb1 = *(const float4*)(krb + 4);
        float4 va0 = *(const float4*)vra;
        float4 va1 = *(const float4*)(vra + 4);
        float4 vb0 = *(const float4*)vrb;
        float4 vb1 = *(const float4*)(vrb + 4);
        float pa = qa0.x*ka0.x + qa0.y*ka0.y + qa0.z*ka0.z + qa0.w*ka0.w
                 + qa1.x*ka1.x + qa1.y*ka1.y + qa1.z*ka1.z + qa1.w*ka1.w;
        float pb = qb0.x*kb0.x + qb0.y*kb0.y + qb0.z*kb0.z + qb0.w*kb0.w
                 + qb1.x*kb1.x + qb1.y*kb1.y + qb1.z*kb1.z + qb1.w*kb1.w;
        pa += __shfl_xor(pa, 1, 64); pb += __shfl_xor(pb, 1, 64);
        pa += __shfl_xor(pa, 2, 64); pb += __shfl_xor(pb, 2, 64);
        pa += __shfl_xor(pa, 4, 64); pb += __shfl_xor(pb, 4, 64);
        float wa = aok ? (__expf(0.125f * pa) - 1.f) : 0.f;
        float wb = __expf(0.125f * pb) - 1.f;
        za += wa; zb += wb;
        na0.x += wa*va0.x; na0.y += wa*va0.y; na0.z += wa*va0.z; na0.w += wa*va0.w;
        na1.x += wa*va1.x; na1.y += wa*va1.y; na1.z += wa*va1.z; na1.w += wa*va1.w;
        nb0.x += wb*vb0.x; nb0.y += wb*vb0.y; nb0.z += wb*vb0.z; nb0.w += wb*vb0.w;
        nb1.x += wb*vb1.x; nb1.y += wb*vb1.y; nb1.z += wb*vb1.z; nb1.w += wb*vb1.w;
    }

    // ---- prefix chunks (identical for both rows): level-2 then level-1
    float4 p0 = make_float4(0.f,0.f,0.f,0.f), p1 = p0;
    const float* cs2 = csum2 + (size_t)bh * NL2_ * D_ + 8 * sub;
    for (int cc = grp; cc < c2; cc += 8) {
        float4 a = *(const float4*)(cs2 + (size_t)cc * D_);
        float4 bq = *(const float4*)(cs2 + (size_t)cc * D_ + 4);
        p0.x += a.x;  p0.y += a.y;  p0.z += a.z;  p0.w += a.w;
        p1.x += bq.x; p1.y += bq.y; p1.z += bq.z; p1.w += bq.w;
    }
    const float* cs1 = csum1 + (size_t)bh * NC_ * D_ + 8 * sub;
    for (int cc = (c2 << 4) + grp; cc < c1; cc += 8) {
        float4 a = *(const float4*)(cs1 + (size_t)cc * D_);
        float4 bq = *(const float4*)(cs1 + (size_t)cc * D_ + 4);
        p0.x += a.x;  p0.y += a.y;  p0.z += a.z;  p0.w += a.w;
        p1.x += bq.x; p1.y += bq.y; p1.z += bq.z; p1.w += bq.w;
    }
    na0.x += p0.x; na0.y += p0.y; na0.z += p0.z; na0.w += p0.w;
    na1.x += p1.x; na1.y += p1.y; na1.z += p1.z; na1.w += p1.w;
    nb0.x += p0.x; nb0.y += p0.y; nb0.z += p0.z; nb0.w += p0.w;
    nb1.x += p1.x; nb1.y += p1.y; nb1.z += p1.z; nb1.w += p1.w;

    // ---- cross-group reduction (xor 8, 16, 32) over 18 values
    #pragma unroll
    for (int m = 8; m <= 32; m <<= 1) {
        na0.x += __shfl_xor(na0.x, m, 64); na0.y += __shfl_xor(na0.y, m, 64);
        na0.z += __shfl_xor(na0.z, m, 64); na0.w += __shfl_xor(na0.w, m, 64);
        na1.x += __shfl_xor(na1.x, m, 64); na1.y += __shfl_xor(na1.y, m, 64);
        na1.z += __shfl_xor(na1.z, m, 64); na1.w += __shfl_xor(na1.w, m, 64);
        nb0.x += __shfl_xor(nb0.x, m, 64); nb0.y += __shfl_xor(nb0.y, m, 64);
        nb0.z += __shfl_xor(nb0.z, m, 64); nb0.w += __shfl_xor(nb0.w, m, 64);
        nb1.x += __shfl_xor(nb1.x, m, 64); nb1.y += __shfl_xor(nb1.y, m, 64);
        nb1.z += __shfl_xor(nb1.z, m, 64); nb1.w += __shfl_xor(nb1.w, m, 64);
        za    += __shfl_xor(za, m, 64);
        zb    += __shfl_xor(zb, m, 64);
    }

    if (grp == 0) {
        float inv = 1.f / (za + (float)(ia + 1));
        float* op = out + ((size_t)(b * L_ + ia) * H_ + hh) * D_ + 8 * sub;
        *(float4*)op       = make_float4(na0.x*inv, na0.y*inv, na0.z*inv, na0.w*inv);
        *(float4*)(op + 4) = make_float4(na1.x*inv, na1.y*inv, na1.z*inv, na1.w*inv);
    } else if (grp == 1) {
        float inv = 1.f / (zb + (float)(ib + 1));
        float* op = out + ((size_t)(b * L_ + ib) * H_ + hh) * D_ + 8 * sub;
        *(float4*)op       = make_float4(nb0.x*inv, nb0.y*inv, nb0.z*inv, nb0.w*inv);
        *(float4*)(op + 4) = make_float4(nb1.x*inv, nb1.y*inv, nb1.z*inv, nb1.w*inv);
    }
}

extern "C" void kernel_launch(void* const* d_in, const int* in_sizes, int n_in,
                              void* d_out, int out_size, void* d_ws, size_t ws_size,
                              hipStream_t stream) {
    const float* q = (const float*)d_in[0];
    const float* k = (const float*)d_in[1];
    const float* v = (const float*)d_in[2];
    // d_in[3] = attn_mask: deterministic causal — not read.
    float* out = (float*)d_out;

    float* csum1 = (float*)d_ws;                         // B*H*NC*D  = 131072 floats
    float* csum2 = csum1 + (size_t)B_ * H_ * NC_ * D_;   // B*H*NL2*D = 8192 floats

    chunk_sums_k<<<B_ * H_ * NC_, 64, 0, stream>>>(v, csum1);
    l2_sums_k   <<<B_ * H_ * NL2_, 64, 0, stream>>>(csum1, csum2);

    int pairs = B_ * H_ * (L_ / 2);   // 16384 waves, 4 per 256-thread block
    dozer_k<<<pairs / 4, 256, 0, stream>>>(q, k, v, csum1, csum2, out);
}